// Round 1
// 1617.664 us; speedup vs baseline: 1.1447x; 1.1447x over previous
//
#include <hip/hip_runtime.h>
#include <stdint.h>

#define M_DIM 8192
#define N_DIM 14336
#define K_DIM 4096

typedef __bf16 bf16x8 __attribute__((ext_vector_type(8)));
typedef float f32x4 __attribute__((ext_vector_type(4)));
typedef uint16_t u16x8 __attribute__((ext_vector_type(8)));

// ---------- helpers ----------

__device__ __forceinline__ uint16_t f2bf(float f) {
  union { float f; uint32_t u; } v; v.f = f;
  uint32_t u = v.u;
  // round-to-nearest-even bf16
  return (uint16_t)((u + 0x7FFFu + ((u >> 16) & 1u)) >> 16);
}

__device__ __forceinline__ void load_lds16(const void* g, void* l) {
  // async global->LDS DMA, 16 B/lane; LDS dest = wave-uniform base + lane*16
  __builtin_amdgcn_global_load_lds(
      (const __attribute__((address_space(1))) uint32_t*)g,
      (__attribute__((address_space(3))) uint32_t*)l,
      16, 0, 0);
}

// ---------- prepass: x fp32 -> bf16 ----------

__global__ __launch_bounds__(256) void cvt_x_kernel(const float4* __restrict__ x,
                                                    u16x8* __restrict__ out, int n) {
  int i = blockIdx.x * 256 + threadIdx.x;
  if (i >= n) return;
  float4 a = x[2 * i], b = x[2 * i + 1];
  u16x8 r;
  r[0] = f2bf(a.x); r[1] = f2bf(a.y); r[2] = f2bf(a.z); r[3] = f2bf(a.w);
  r[4] = f2bf(b.x); r[5] = f2bf(b.y); r[6] = f2bf(b.z); r[7] = f2bf(b.w);
  out[i] = r;
}

// ---------- prepass: int4-packed weights -> bf16 integer values ----------
// (harness delivers qweight as one packed byte per int32 element)

__global__ __launch_bounds__(256) void dequant_w_kernel(const int4* __restrict__ qw,
                                                        u16x8* __restrict__ out, int n) {
  int i = blockIdx.x * 256 + threadIdx.x;
  if (i >= n) return;
  int4 p = qw[i];
  int v[4] = {p.x, p.y, p.z, p.w};
  u16x8 r;
#pragma unroll
  for (int b = 0; b < 4; b++) {
    int byte = (int)(int8_t)(v[b] & 0xFF);       // robust sign-extend either convention
    int hi = byte >> 4;                           // arithmetic shift
    int lo = ((byte & 15) ^ 8) - 8;               // sign-extend low nibble
    r[2 * b]     = f2bf((float)hi);               // element 2j   = high nibble
    r[2 * b + 1] = f2bf((float)lo);               // element 2j+1 = low nibble
  }
  out[i] = r;
}

// ---------- main GEMM: 256x256 tile, BK=64, 8 waves (2Mx4N), 8-phase pipeline ----------
// m201-style schedule: counted vmcnt (never 0 in loop), XOR-swizzled LDS via
// pre-swizzled global_load_lds sources (write linear, swizzle the ds_read),
// setprio around MFMA clusters, XCD-bijective block swizzle, NT stores for C.
//
// Schedule proof sketch (per-wave vmcnt counts 2 stage-instructions per phase):
//   tile kt (buf b=kt&1), phases P0..P3:
//     P0: ds_read Q(0,0) frags of kt; stage A-units {0,2} of kt+1 -> buf b^1
//     P1: ds_read Q(1,1) frags of kt; stage A-units {1,3} of kt+1 -> buf b^1
//     P2:                              stage B-units {0,1} of kt+2 -> buf b
//     P3:                              stage B-units {2,3} of kt+2 -> buf b
//         vmcnt(4) -> everything older than P2/P3's 4 loads has landed,
//         i.e. all of kt+1's A units and kt+1's B units (staged at kt-1.P2/P3).
//   LDS-overwrite safety: all ds_reads of tile kt complete by end of P1
//   (barrier'd), so staging kt+2's B into buf b at P2/P3 is race-free, and
//   staging kt+1's A into buf b^1 at P0/P1 is >=2 phases after kt-1's last read.

#define SBAR      asm volatile("s_barrier" ::: "memory")
#define LGKM0     do { asm volatile("s_waitcnt lgkmcnt(0)" ::: "memory"); \
                       __builtin_amdgcn_sched_barrier(0); } while (0)
#define VMCNT(n_) asm volatile("s_waitcnt vmcnt(" #n_ ")" ::: "memory")

#define RD_A(b_, kh_, mi_) \
  af[kh_][mi_] = *(const bf16x8*)(ldsA + (b_) * 32768 + ((kh_) ? aoff1 : aoff0) + (mi_) * 2048)
#define RD_B(b_, kh_, ni_) \
  bfr[kh_][ni_] = *(const bf16x8*)(ldsB + (b_) * 32768 + ((kh_) ? boff1 : boff0) + (ni_) * 2048)

#define STGA(b_, u_, kt2_) \
  load_lds16(gA + (size_t)((u_) * 64 + trow) * K_DIM + (size_t)(kt2_) * 64 + tslot * 8, \
             &As[b_][(u_) * 64 + (wave << 3)][0])
#define STGB(b_, u_, kt2_) \
  load_lds16(gB + (size_t)((u_) * 64 + trow) * K_DIM + (size_t)(kt2_) * 64 + tslot * 8, \
             &Bs[b_][(u_) * 64 + (wave << 3)][0])

#define MM(kh_, mi_, ni_) \
  acc[mi_][ni_] = __builtin_amdgcn_mfma_f32_16x16x32_bf16(af[kh_][mi_], bfr[kh_][ni_], acc[mi_][ni_], 0, 0, 0)
#define MQ(qm_, qn_) do { \
  MM(0,(qm_)*4+0,(qn_)*2+0); MM(1,(qm_)*4+0,(qn_)*2+0); \
  MM(0,(qm_)*4+1,(qn_)*2+0); MM(1,(qm_)*4+1,(qn_)*2+0); \
  MM(0,(qm_)*4+2,(qn_)*2+0); MM(1,(qm_)*4+2,(qn_)*2+0); \
  MM(0,(qm_)*4+3,(qn_)*2+0); MM(1,(qm_)*4+3,(qn_)*2+0); \
  MM(0,(qm_)*4+0,(qn_)*2+1); MM(1,(qm_)*4+0,(qn_)*2+1); \
  MM(0,(qm_)*4+1,(qn_)*2+1); MM(1,(qm_)*4+1,(qn_)*2+1); \
  MM(0,(qm_)*4+2,(qn_)*2+1); MM(1,(qm_)*4+2,(qn_)*2+1); \
  MM(0,(qm_)*4+3,(qn_)*2+1); MM(1,(qm_)*4+3,(qn_)*2+1); \
} while (0)

#define TILE(kt_, B_) do { \
  const int ktn_  = ((kt_) + 1 < NKT) ? (kt_) + 1 : NKT - 1; \
  const int ktn2_ = ((kt_) + 2 < NKT) ? (kt_) + 2 : NKT - 1; \
  /* P0: frags for Q(0,0); prefetch kt+1 A-units 0,2 */ \
  RD_A(B_,0,0); RD_A(B_,1,0); RD_A(B_,0,1); RD_A(B_,1,1); \
  RD_A(B_,0,2); RD_A(B_,1,2); RD_A(B_,0,3); RD_A(B_,1,3); \
  RD_B(B_,0,0); RD_B(B_,1,0); RD_B(B_,0,1); RD_B(B_,1,1); \
  STGA((B_)^1, 0, ktn_); STGA((B_)^1, 2, ktn_); \
  SBAR; LGKM0; \
  __builtin_amdgcn_s_setprio(1); MQ(0,0); __builtin_amdgcn_s_setprio(0); \
  SBAR; \
  /* P1: frags for Q(1,1); prefetch kt+1 A-units 1,3 */ \
  RD_A(B_,0,4); RD_A(B_,1,4); RD_A(B_,0,5); RD_A(B_,1,5); \
  RD_A(B_,0,6); RD_A(B_,1,6); RD_A(B_,0,7); RD_A(B_,1,7); \
  RD_B(B_,0,2); RD_B(B_,1,2); RD_B(B_,0,3); RD_B(B_,1,3); \
  STGA((B_)^1, 1, ktn_); STGA((B_)^1, 3, ktn_); \
  SBAR; LGKM0; \
  __builtin_amdgcn_s_setprio(1); MQ(1,1); __builtin_amdgcn_s_setprio(0); \
  SBAR; \
  /* P2: prefetch kt+2 B-units 0,1 */ \
  STGB(B_, 0, ktn2_); STGB(B_, 1, ktn2_); \
  SBAR; \
  __builtin_amdgcn_s_setprio(1); MQ(1,0); __builtin_amdgcn_s_setprio(0); \
  SBAR; \
  /* P3: prefetch kt+2 B-units 2,3; counted wait */ \
  STGB(B_, 2, ktn2_); STGB(B_, 3, ktn2_); \
  SBAR; \
  __builtin_amdgcn_s_setprio(1); MQ(0,1); __builtin_amdgcn_s_setprio(0); \
  VMCNT(4); \
  SBAR; \
} while (0)

__global__ __launch_bounds__(512, 2) void gemm256_kernel(
    const uint16_t* __restrict__ A, const uint16_t* __restrict__ B,
    const float* __restrict__ scale, const float* __restrict__ bias,
    float* __restrict__ C) {
  constexpr int NKT = K_DIM / 64;  // 64 K-tiles
  static_assert(M_DIM % 256 == 0 && N_DIM % 256 == 0 && (NKT % 2) == 0, "shape");

  __shared__ alignas(16) uint16_t As[2][256][64];  // 64 KB
  __shared__ alignas(16) uint16_t Bs[2][256][64];  // 64 KB

  const int tid = threadIdx.x;
  const int lane = tid & 63;
  const int wave = tid >> 6;
  const int wm = wave >> 2;  // 0..1 -> 128 M-rows each
  const int wn = wave & 3;   // 0..3 -> 64 N-cols each

  // XCD-bijective swizzle: 1792 = 8 XCDs * 224; within an XCD, bm varies
  // fastest in groups of 4 so concurrent blocks share B panels in L2.
  const int orig = blockIdx.x;
  const int xcd = orig & 7;
  const int local = orig >> 3;               // 0..223
  const int bm = xcd * 4 + (local & 3);      // 0..31
  const int bn = local >> 2;                 // 0..55
  const int mBase = bm * 256, nBase = bn * 256;

  const uint16_t* gA = A + (size_t)mBase * K_DIM;
  const uint16_t* gB = B + (size_t)nBase * K_DIM;

  // staging coords: thread t covers LDS row t/8, 16B slot t%8 of an 8KB unit.
  // LDS is written linearly; the SOURCE slot is pre-swizzled (slot ^ row&7).
  const int trow = tid >> 3;
  const int tslot = (tid & 7) ^ (trow & 7);

  // ds_read coords: A[m=lane&15][k=(lane>>4)*8+j]; swizzled slot on read side.
  const int fr = lane & 15;
  const int fc = lane >> 4;
  const int s7 = fr & 7;
  const int aoff0 = (wm * 128 + fr) * 128 + ((fc    ) ^ s7) * 16;
  const int aoff1 = (wm * 128 + fr) * 128 + ((fc + 4) ^ s7) * 16;
  const int boff0 = (wn * 64 + fr) * 128 + ((fc    ) ^ s7) * 16;
  const int boff1 = (wn * 64 + fr) * 128 + ((fc + 4) ^ s7) * 16;
  const char* ldsA = (const char*)As;
  const char* ldsB = (const char*)Bs;

  bf16x8 af[2][8], bfr[2][4];
  f32x4 acc[8][4] = {};

  // ---- prologue: tile0 fully + tile1's B units; leave tile1 B in flight ----
  STGB(0, 0, 0); STGB(0, 1, 0); STGB(0, 2, 0); STGB(0, 3, 0);
  STGA(0, 0, 0); STGA(0, 2, 0);
  STGA(0, 1, 0); STGA(0, 3, 0);
  STGB(1, 0, 1); STGB(1, 1, 1); STGB(1, 2, 1); STGB(1, 3, 1);
  VMCNT(4);
  SBAR;

#pragma unroll 1
  for (int kt = 0; kt < NKT; kt += 2) {
    TILE(kt, 0);
    TILE(kt + 1, 1);
  }

  // drain dangling clamped prefetches before LDS goes away
  asm volatile("s_waitcnt vmcnt(0)" ::: "memory");

  // ---- epilogue: C/D layout col=lane&15, row=(lane>>4)*4+reg; NT stores ----
#pragma unroll
  for (int ni = 0; ni < 4; ++ni) {
    const int cg = nBase + wn * 64 + ni * 16 + fr;
    const float s = scale[cg];
    const float bb = bias[cg];
#pragma unroll
    for (int mi = 0; mi < 8; ++mi) {
      const size_t rg = (size_t)(mBase + wm * 128 + mi * 16 + fc * 4);
#pragma unroll
      for (int r = 0; r < 4; ++r)
        __builtin_nontemporal_store(acc[mi][ni][r] * s + bb,
                                    &C[(rg + r) * N_DIM + cg]);
    }
  }
}

// ---------- slow-but-correct fallback (only if ws_size is insufficient) ----------

__global__ __launch_bounds__(256) void fallback_kernel(
    const float* __restrict__ x, const int* __restrict__ qw,
    const float* __restrict__ scale, const float* __restrict__ bias,
    float* __restrict__ out) {
  int n = blockIdx.x * 256 + threadIdx.x;
  int m = blockIdx.y;
  const int* wr = qw + (size_t)n * (K_DIM / 2);
  const float* xr = x + (size_t)m * K_DIM;
  float acc = 0.f;
  for (int j = 0; j < K_DIM / 2; j++) {
    int byte = (int)(int8_t)(wr[j] & 0xFF);
    int hi = byte >> 4;
    int lo = ((byte & 15) ^ 8) - 8;
    acc += xr[2 * j] * (float)hi + xr[2 * j + 1] * (float)lo;
  }
  out[(size_t)m * N_DIM + n] = acc * scale[n] + bias[n];
}

// ---------- launch ----------

extern "C" void kernel_launch(void* const* d_in, const int* in_sizes, int n_in,
                              void* d_out, int out_size, void* d_ws, size_t ws_size,
                              hipStream_t stream) {
  const float* x = (const float*)d_in[0];
  const int* qw = (const int*)d_in[1];
  const float* scale = (const float*)d_in[2];
  const float* bias = (const float*)d_in[3];
  float* out = (float*)d_out;

  const size_t xb_bytes = (size_t)M_DIM * K_DIM * 2;  //  67,108,864
  const size_t wb_bytes = (size_t)N_DIM * K_DIM * 2;  // 117,440,512

  if (ws_size < xb_bytes + wb_bytes) {
    dim3 g(N_DIM / 256, M_DIM);
    fallback_kernel<<<g, 256, 0, stream>>>(x, qw, scale, bias, out);
    return;
  }

  uint16_t* xb = (uint16_t*)d_ws;
  uint16_t* wb = (uint16_t*)((char*)d_ws + xb_bytes);

  const int n8x = M_DIM * K_DIM / 8;  // 4,194,304 threads -> 16384 blocks
  cvt_x_kernel<<<dim3(n8x / 256), 256, 0, stream>>>((const float4*)x, (u16x8*)xb, n8x);

  const int n4w = N_DIM * K_DIM / 8;  // 7,340,032 threads -> 28672 blocks
  dequant_w_kernel<<<dim3(n4w / 256), 256, 0, stream>>>((const int4*)qw, (u16x8*)wb, n4w);

  gemm256_kernel<<<dim3((M_DIM / 256) * (N_DIM / 256)), 512, 0, stream>>>(
      xb, wb, scale, bias, out);
}